// Round 10
// baseline (172.450 us; speedup 1.0000x reference)
//
#include <hip/hip_runtime.h>

// Problem constants (match reference)
#define LSEQ 2048   // sequence length
#define NS   1022   // number of distances s = 2..1023
#define NF   5110   // NS * 5 output features
#define NB   8      // batch
#define IT   16     // i-positions per block
#define TPB  256    // one block covers ALL s: 256 lanes x 4 s = 1024 >= 1022

// pairing score: 2*y0*z3 + 3*y1*z2 + 3*y2*z1 + 2*y3*z0
__device__ __forceinline__ float cscore(const float4 y, const float4 z) {
    return 2.f * y.x * z.w + 3.f * y.y * z.z + 3.f * y.z * z.y + 2.f * y.w * z.x;
}

// clamped load: zero outside [0, LSEQ)
__device__ __forceinline__ float4 loadx(const float4* __restrict__ xg, int p) {
    int pc = p < 0 ? 0 : (p > LSEQ - 1 ? LSEQ - 1 : p);
    float4 v = xg[pc];
    if ((unsigned)p >= (unsigned)LSEQ) v = make_float4(0.f, 0.f, 0.f, 0.f);
    return v;
}

// No LDS, no barriers: each lane owns 4 consecutive s (20 consecutive output
// floats = 5 aligned float4 stores fed straight from VALU registers).
__global__ __launch_bounds__(TPB) void fdcnn_kernel(const float4* __restrict__ x,
                                                    float* __restrict__ out) {
    const int gl = threadIdx.x;            // 0..255
    const int slane = 4 * gl + 2;          // lane's first distance s
    const int fbase = gl * 20;             // lane's first output feature
    const int i0 = blockIdx.x * IT;
    const int n  = blockIdx.y;
    const float4* xg = x + (size_t)n * LSEQ;

    // Rolling 6-wide windows: Y[d] = x[i + slane + 1 + d], Z[d] = x[i - slane - 1 - d]
    // covering y_d'(s)=x[i+s+d'] and z_d'(s)=x[i-s-d'] for all s in [slane, slane+3], d' in [1,3].
    float4 Y[6], Z[6];
    #pragma unroll
    for (int d = 0; d < 6; ++d) {
        Y[d] = loadx(xg, i0 + slane + 1 + d);
        Z[d] = loadx(xg, i0 - slane - 1 - d);
    }

    float* orow = out + ((size_t)n * LSEQ + i0) * (size_t)NF + fbase;
    const bool full = (fbase + 20) <= NF;   // false only for lane 255 (10 valid floats)

    #pragma unroll 4
    for (int ii = 0; ii < IT; ++ii) {
        // s = slane + k:  y_d = Y[k+d-1], z_d = Z[k+d-1]
        float o[4][5];
        #pragma unroll
        for (int k = 0; k < 4; ++k) {
            o[k][0] = cscore(Y[k], Z[k]) + 2.f * (Y[k].z * Z[k].w + Y[k].w * Z[k].z);
            o[k][1] = cscore(Y[k],     Z[k + 1]);   // left bulge d=1
            o[k][2] = cscore(Y[k],     Z[k + 2]);   // left bulge d=2
            o[k][3] = cscore(Y[k + 1], Z[k]);       // right bulge d=1
            o[k][4] = cscore(Y[k + 2], Z[k]);       // right bulge d=2
        }

        // pack 20 floats -> 5 float4, store register-direct (no LDS readback)
        if (full) {
            #pragma unroll
            for (int m = 0; m < 5; ++m) {
                const float4 v = make_float4(o[(4*m+0)/5][(4*m+0)%5],
                                             o[(4*m+1)/5][(4*m+1)%5],
                                             o[(4*m+2)/5][(4*m+2)%5],
                                             o[(4*m+3)/5][(4*m+3)%5]);
                *(float4*)(orow + 4 * m) = v;
            }
        } else {
            *(float4*)(orow + 0) = make_float4(o[0][0], o[0][1], o[0][2], o[0][3]);
            *(float4*)(orow + 4) = make_float4(o[0][4], o[1][0], o[1][1], o[1][2]);
            *(float2*)(orow + 8) = make_float2(o[1][3], o[1][4]);
        }

        // roll windows: y gains at far end, z gains at near end
        const int inext = i0 + ii + 1;
        #pragma unroll
        for (int d = 0; d < 5; ++d) Y[d] = Y[d + 1];
        Y[5] = loadx(xg, inext + slane + 6);
        #pragma unroll
        for (int d = 5; d > 0; --d) Z[d] = Z[d - 1];
        Z[0] = loadx(xg, inext - slane - 1);

        orow += NF;
    }
}

extern "C" void kernel_launch(void* const* d_in, const int* in_sizes, int n_in,
                              void* d_out, int out_size, void* d_ws, size_t ws_size,
                              hipStream_t stream) {
    const float4* x = (const float4*)d_in[0];
    float* out = (float*)d_out;
    dim3 grid(LSEQ / IT, NB);   // (128, 8) = 1024 blocks, zero LDS
    dim3 block(TPB);
    fdcnn_kernel<<<grid, block, 0, stream>>>(x, out);
}